// Round 1
// baseline (2375.844 us; speedup 1.0000x reference)
//
#include <hip/hip_runtime.h>
#include <hip/hip_bf16.h>

// Problem constants
#define Hdim 1024
#define Nb   2048
#define Lsteps 48

typedef unsigned short ushort_t;
typedef short bf16x8 __attribute__((ext_vector_type(8)));   // 8 bf16 (4 VGPRs)
typedef float f32x4 __attribute__((ext_vector_type(4)));    // 4 fp32 accum

// RTN-even fp32 -> bf16 bits
__device__ __forceinline__ ushort_t f2bf(float x) {
    unsigned u = __builtin_bit_cast(unsigned, x);
    unsigned r = u + 0x7fffu + ((u >> 16) & 1u);
    return (ushort_t)(r >> 16);
}

__device__ __forceinline__ float fsigmoid(float x) {
    return 1.0f / (1.0f + __expf(-x));
}
__device__ __forceinline__ float ftanh(float x) {
    float xm = fminf(fmaxf(x, -15.0f), 15.0f);
    float e = __expf(2.0f * xm);
    return (e - 1.0f) / (e + 1.0f);
}

__device__ __forceinline__ f32x4 mfma16(bf16x8 a, bf16x8 b, f32x4 c) {
    return __builtin_amdgcn_mfma_f32_16x16x32_bf16(a, b, c, 0, 0, 0);
}

// ---------------------------------------------------------------------------
// Prep kernels (run once per kernel_launch; ws is re-poisoned every call)
// ---------------------------------------------------------------------------
__global__ __launch_bounds__(256) void prep_w(const float* __restrict__ W,
                                              ushort_t* __restrict__ Wb) {
    int i = blockIdx.x * 256 + threadIdx.x;   // 4M elements
    Wb[i] = f2bf(W[i]);
}

__global__ __launch_bounds__(256) void prep_h(const float* __restrict__ h_in,
                                              ushort_t* __restrict__ h0,
                                              const float* __restrict__ b_ih,
                                              const float* __restrict__ b_hh,
                                              float* __restrict__ bias) {
    int i = blockIdx.x * 256 + threadIdx.x;   // 2M elements
    h0[i] = f2bf(h_in[i]);
    if (i < 4 * Hdim) bias[i] = b_ih[i] + b_hh[i];
}

// ---------------------------------------------------------------------------
// Fused step kernel: z = h @ W^T + bias; gates; c/h update; h -> hdst(bf16),
// h -> tmp slot (fp32, coalesced [n][j] layout; transposed to out later).
// Block: 64 n-rows x 64 j-cols x 4 gates. 4 waves in 2x2; each wave 32x32x4g.
// ---------------------------------------------------------------------------
__global__ __launch_bounds__(256) void lstm_step(
    const ushort_t* __restrict__ hsrc,   // [Nb][Hdim] bf16 bits
    ushort_t* __restrict__ hdst,         // [Nb][Hdim] bf16 bits
    const ushort_t* __restrict__ Wb,     // [4*Hdim][Hdim] bf16 bits
    const float* __restrict__ bias,      // [4*Hdim]
    float* __restrict__ cst,             // [Nb][Hdim] fp32 cell state
    float* __restrict__ tmp)             // [Nb][Hdim] fp32 h output slot
{
    // LDS tiles, padded stride 40 bf16 (80 B = 20 banks -> 2-way max, free)
    __shared__ __align__(16) ushort_t As[64 * 40];     // 5.0 KB
    __shared__ __align__(16) ushort_t Bs[256 * 40];    // 20.0 KB

    const int tid  = threadIdx.x;
    const int lane = tid & 63;
    const int wid  = tid >> 6;
    const int wr   = wid >> 1;           // wave row (0..1)
    const int wc   = wid & 1;            // wave col (0..1)
    const int rb   = blockIdx.x & 31;    // 32 row blocks
    const int jb   = blockIdx.x >> 5;    // 16 col blocks
    const int n0   = rb * 64;
    const int j0   = jb * 64;

    f32x4 acc[4][2][2];
#pragma unroll
    for (int g = 0; g < 4; ++g)
#pragma unroll
        for (int a = 0; a < 2; ++a)
#pragma unroll
            for (int b = 0; b < 2; ++b)
                acc[g][a][b] = (f32x4){0.f, 0.f, 0.f, 0.f};

    const int srow = tid >> 2;          // 0..63
    const int sks  = (tid & 3) * 8;     // 0,8,16,24 (bf16 elems)
    const int lr   = lane & 15;
    const int kq   = (lane >> 4) * 8;

    for (int kc = 0; kc < 32; ++kc) {
        const int k0 = kc * 32;
        __syncthreads();
        // stage A tile: 64 rows x 32 k  (16 B per thread)
        {
            uint4 av = *(const uint4*)(hsrc + (size_t)(n0 + srow) * Hdim + k0 + sks);
            *(uint4*)&As[srow * 40 + sks] = av;
        }
        // stage B tile: 256 W-rows x 32 k (4 x 16 B per thread)
#pragma unroll
        for (int r = 0; r < 4; ++r) {
            int u  = srow + r * 64;              // 0..255, = g*64 + jl
            int g  = u >> 6;
            int jl = u & 63;
            int grow = g * Hdim + j0 + jl;       // W row index
            uint4 bv = *(const uint4*)(Wb + (size_t)grow * Hdim + k0 + sks);
            *(uint4*)&Bs[u * 40 + sks] = bv;
        }
        __syncthreads();

        bf16x8 a0 = *(const bf16x8*)&As[(wr * 32 + lr) * 40 + kq];
        bf16x8 a1 = *(const bf16x8*)&As[(wr * 32 + 16 + lr) * 40 + kq];
#pragma unroll
        for (int g = 0; g < 4; ++g) {
            bf16x8 b0 = *(const bf16x8*)&Bs[(g * 64 + wc * 32 + lr) * 40 + kq];
            bf16x8 b1 = *(const bf16x8*)&Bs[(g * 64 + wc * 32 + 16 + lr) * 40 + kq];
            acc[g][0][0] = mfma16(a0, b0, acc[g][0][0]);
            acc[g][0][1] = mfma16(a0, b1, acc[g][0][1]);
            acc[g][1][0] = mfma16(a1, b0, acc[g][1][0]);
            acc[g][1][1] = mfma16(a1, b1, acc[g][1][1]);
        }
    }

    // Epilogue: C/D layout col=lane&15, row=(lane>>4)*4+reg  [m89-verified]
    const int q4 = (lane >> 4) * 4;
#pragma unroll
    for (int rt = 0; rt < 2; ++rt)
#pragma unroll
        for (int ct = 0; ct < 2; ++ct)
#pragma unroll
            for (int q = 0; q < 4; ++q) {
                int n = n0 + wr * 32 + rt * 16 + q4 + q;
                int j = j0 + wc * 32 + ct * 16 + lr;
                float zi = acc[0][rt][ct][q] + bias[j];
                float zf = acc[1][rt][ct][q] + bias[Hdim + j];
                float zg = acc[2][rt][ct][q] + bias[2 * Hdim + j];
                float zo = acc[3][rt][ct][q] + bias[3 * Hdim + j];
                float gi = fsigmoid(zi);
                float gf = fsigmoid(zf);
                float gg = ftanh(zg);
                float go = fsigmoid(zo);
                size_t idx = (size_t)n * Hdim + j;
                float cn = gf * cst[idx] + gi * gg;
                cst[idx] = cn;
                float hv = go * ftanh(cn);
                hdst[idx] = f2bf(hv);
                tmp[idx] = hv;
            }
}

// ---------------------------------------------------------------------------
// Flush: tmp[16][Nb][Hdim] -> out[n][j][t0 : t0+16]  (full 64B lines per thread)
// ---------------------------------------------------------------------------
__global__ __launch_bounds__(256) void flush16(const float* __restrict__ tmp,
                                               float* __restrict__ out, int t0) {
    int idx = blockIdx.x * 256 + threadIdx.x;   // 0 .. Nb*Hdim-1
    float v[16];
#pragma unroll
    for (int s = 0; s < 16; ++s)
        v[s] = tmp[(size_t)s * (Nb * Hdim) + idx];
    float4* dst = (float4*)(out + (size_t)idx * Lsteps + t0);
#pragma unroll
    for (int s = 0; s < 4; ++s)
        dst[s] = make_float4(v[4 * s], v[4 * s + 1], v[4 * s + 2], v[4 * s + 3]);
}

// ---------------------------------------------------------------------------
extern "C" void kernel_launch(void* const* d_in, const int* in_sizes, int n_in,
                              void* d_out, int out_size, void* d_ws, size_t ws_size,
                              hipStream_t stream) {
    const float* h_in = (const float*)d_in[0];
    const float* W    = (const float*)d_in[1];
    const float* b_ih = (const float*)d_in[2];
    const float* b_hh = (const float*)d_in[3];
    float* out = (float*)d_out;

    // Workspace layout (bytes):
    //   Wb     @ 0          : 4096*1024*2 = 8388608
    //   h0     @ 8388608    : 2048*1024*2 = 4194304
    //   h1     @ 12582912   : 2048*1024*2 = 4194304
    //   c      @ 16777216   : 2048*1024*4 = 8388608
    //   bias   @ 25165824   : 4096*4      = 16384
    //   tmp16  @ 25182208   : 16*2048*1024*4 = 134217728   (total ~159.4 MB)
    char* ws = (char*)d_ws;
    ushort_t* Wb   = (ushort_t*)(ws);
    ushort_t* h0   = (ushort_t*)(ws + 8388608);
    ushort_t* h1   = (ushort_t*)(ws + 12582912);
    float*    cst  = (float*)(ws + 16777216);
    float*    bias = (float*)(ws + 25165824);
    float*    tmp16= (float*)(ws + 25182208);

    // c starts at zero every call (ws is poisoned 0xAA each timed launch)
    hipMemsetAsync(cst, 0, (size_t)Nb * Hdim * sizeof(float), stream);

    prep_w<<<(4 * Hdim * Hdim) / 256, 256, 0, stream>>>(W, Wb);
    prep_h<<<(Nb * Hdim) / 256, 256, 0, stream>>>(h_in, h0, b_ih, b_hh, bias);

    for (int t = 0; t < Lsteps; ++t) {
        const ushort_t* hs = (t & 1) ? h1 : h0;
        ushort_t*       hd = (t & 1) ? h0 : h1;
        float* tslot = tmp16 + (size_t)(t & 15) * (Nb * Hdim);
        lstm_step<<<512, 256, 0, stream>>>(hs, hd, Wb, bias, cst, tslot);
        if ((t & 15) == 15) {
            flush16<<<(Nb * Hdim) / 256, 256, 0, stream>>>(tmp16, out, t - 15);
        }
    }
}

// Round 2
// 1905.648 us; speedup vs baseline: 1.2467x; 1.2467x over previous
//
#include <hip/hip_runtime.h>
#include <hip/hip_bf16.h>

// Problem constants
#define Hdim 1024
#define Nb   2048
#define Lsteps 48

typedef unsigned short ushort_t;
typedef short bf16x8 __attribute__((ext_vector_type(8)));   // 8 bf16 (4 VGPRs)
typedef float f32x4 __attribute__((ext_vector_type(4)));    // 4 fp32 accum

typedef __attribute__((address_space(3))) unsigned int lds_u32;
typedef const __attribute__((address_space(1))) unsigned int glb_u32;

__device__ __forceinline__ void gll16(const void* g, void* l) {
    // async global->LDS DMA, 16 B/lane; LDS dest = wave-uniform base + lane*16
    __builtin_amdgcn_global_load_lds((glb_u32*)g, (lds_u32*)l, 16, 0, 0);
}

// RTN-even fp32 -> bf16 bits
__device__ __forceinline__ ushort_t f2bf(float x) {
    unsigned u = __builtin_bit_cast(unsigned, x);
    unsigned r = u + 0x7fffu + ((u >> 16) & 1u);
    return (ushort_t)(r >> 16);
}

__device__ __forceinline__ float fsigmoid(float x) {
    return 1.0f / (1.0f + __expf(-x));
}
__device__ __forceinline__ float ftanh(float x) {
    float xm = fminf(fmaxf(x, -15.0f), 15.0f);
    float e = __expf(2.0f * xm);
    return (e - 1.0f) / (e + 1.0f);
}

__device__ __forceinline__ f32x4 mfma16(bf16x8 a, bf16x8 b, f32x4 c) {
    return __builtin_amdgcn_mfma_f32_16x16x32_bf16(a, b, c, 0, 0, 0);
}

// ---------------------------------------------------------------------------
// Prep kernels
// ---------------------------------------------------------------------------
__global__ __launch_bounds__(256) void prep_w(const float* __restrict__ W,
                                              ushort_t* __restrict__ Wb) {
    int i = blockIdx.x * 256 + threadIdx.x;   // 4M elements
    Wb[i] = f2bf(W[i]);
}

__global__ __launch_bounds__(256) void prep_h(const float* __restrict__ h_in,
                                              ushort_t* __restrict__ h0,
                                              const float* __restrict__ b_ih,
                                              const float* __restrict__ b_hh,
                                              float* __restrict__ bias) {
    int i = blockIdx.x * 256 + threadIdx.x;   // 2M elements
    h0[i] = f2bf(h_in[i]);
    if (i < 4 * Hdim) bias[i] = b_ih[i] + b_hh[i];
}

// ---------------------------------------------------------------------------
// Fused step: tile = 128 n-rows x 32 j-cols x 4 gates (GEMM 128x128), BK=64.
// Staging via global_load_lds(16B) into XOR-swizzled unpadded LDS.
// 4 waves 2x2: wr = n-half (64 rows), wc = j-half (16 cols); each wave also
// stages gate g==wid's W rows (u = wid*32 + 0..31 <=> g = wid).
// ---------------------------------------------------------------------------
__global__ __launch_bounds__(256) void lstm_step(
    const ushort_t* __restrict__ hsrc,   // [Nb][Hdim] bf16 bits
    ushort_t* __restrict__ hdst,         // [Nb][Hdim] bf16 bits
    const ushort_t* __restrict__ Wb,     // [4*Hdim][Hdim] bf16 bits
    const float* __restrict__ bias,      // [4*Hdim]
    float* __restrict__ cst,             // [Nb][Hdim] fp32 cell state
    float* __restrict__ tmp)             // [Nb][Hdim] fp32 h output slot
{
    // 128 rows x 64 elems (128 B) each, unpadded (gll requirement).
    __shared__ __align__(16) ushort_t As[128 * 64];    // 16 KB
    __shared__ __align__(16) ushort_t Bs[128 * 64];    // 16 KB

    const int tid  = threadIdx.x;
    const int lane = tid & 63;
    const int wid  = tid >> 6;
    const int wr   = wid >> 1;            // n half (0..1)
    const int wc   = wid & 1;             // j half (0..1)
    const int nb   = blockIdx.x & 15;     // 16 n-blocks
    const int jb   = blockIdx.x >> 4;     // 32 j-blocks
    const int n0   = nb * 128;
    const int j0   = jb * 32;

    f32x4 acc[4][4];
#pragma unroll
    for (int g = 0; g < 4; ++g)
#pragma unroll
        for (int ri = 0; ri < 4; ++ri)
            acc[g][ri] = (f32x4){0.f, 0.f, 0.f, 0.f};

    // staging geometry: per gll instr, 8 rows x 128 B; lane -> (row, chunk)
    const int srow8  = lane >> 3;                      // row within group of 8
    const int schunk = (lane & 7) ^ srow8;             // swizzled 16B chunk
    const int choff  = schunk * 8;                     // elem offset in row

    // per-lane global row base pointers (row stride Hdim elems)
    const ushort_t* aGlob = hsrc + (size_t)(n0 + wid * 32 + srow8) * Hdim + choff;
    const ushort_t* bGlob = Wb + (size_t)(wid * Hdim + j0 + srow8) * Hdim + choff;

    // ds_read swizzle: row&7 == lr&7 for both A and B fragment rows
    const int lr   = lane & 15;
    const int rsw  = lr & 7;
    const int cq   = lane >> 4;                        // base chunk 0..3

    for (int it = 0; it < 16; ++it) {
        const int k0 = it * 64;
        __syncthreads();
#pragma unroll
        for (int ii = 0; ii < 4; ++ii) {
            gll16(aGlob + (size_t)ii * 8 * Hdim + k0, &As[(wid * 32 + ii * 8) * 64]);
        }
#pragma unroll
        for (int ii = 0; ii < 4; ++ii) {
            gll16(bGlob + (size_t)ii * 8 * Hdim + k0, &Bs[(wid * 32 + ii * 8) * 64]);
        }
        __syncthreads();

#pragma unroll
        for (int kh = 0; kh < 2; ++kh) {
            const int ch = ((cq + kh * 4) ^ rsw) * 8;  // swizzled elem offset
            bf16x8 af[4], bfr[4];
#pragma unroll
            for (int ri = 0; ri < 4; ++ri) {
                int row = wr * 64 + ri * 16 + lr;
                af[ri] = *(const bf16x8*)&As[row * 64 + ch];
            }
#pragma unroll
            for (int g = 0; g < 4; ++g) {
                int u = g * 32 + wc * 16 + lr;
                bfr[g] = *(const bf16x8*)&Bs[u * 64 + ch];
            }
#pragma unroll
            for (int g = 0; g < 4; ++g)
#pragma unroll
                for (int ri = 0; ri < 4; ++ri)
                    acc[g][ri] = mfma16(af[ri], bfr[g], acc[g][ri]);
        }
    }

    // Epilogue: C/D layout col=lane&15, row=(lane>>4)*4+reg  [m89-verified]
    const int q4 = (lane >> 4) * 4;
    const int j  = j0 + wc * 16 + lr;
    const float bi = bias[j];
    const float bf = bias[Hdim + j];
    const float bg = bias[2 * Hdim + j];
    const float bo = bias[3 * Hdim + j];
#pragma unroll
    for (int ri = 0; ri < 4; ++ri)
#pragma unroll
        for (int q = 0; q < 4; ++q) {
            int n = n0 + wr * 64 + ri * 16 + q4 + q;
            float gi = fsigmoid(acc[0][ri][q] + bi);
            float gf = fsigmoid(acc[1][ri][q] + bf);
            float gg = ftanh(acc[2][ri][q] + bg);
            float go = fsigmoid(acc[3][ri][q] + bo);
            size_t idx = (size_t)n * Hdim + j;
            float cn = gf * cst[idx] + gi * gg;
            cst[idx] = cn;
            float hv = go * ftanh(cn);
            hdst[idx] = f2bf(hv);
            tmp[idx] = hv;
        }
}

// ---------------------------------------------------------------------------
// Flush: tmp[16][Nb][Hdim] -> out[n][j][t0 : t0+16]  (full 64B lines)
// ---------------------------------------------------------------------------
__global__ __launch_bounds__(256) void flush16(const float* __restrict__ tmp,
                                               float* __restrict__ out, int t0) {
    int idx = blockIdx.x * 256 + threadIdx.x;   // 0 .. Nb*Hdim-1
    float v[16];
#pragma unroll
    for (int s = 0; s < 16; ++s)
        v[s] = tmp[(size_t)s * (Nb * Hdim) + idx];
    float4* dst = (float4*)(out + (size_t)idx * Lsteps + t0);
#pragma unroll
    for (int s = 0; s < 4; ++s)
        dst[s] = make_float4(v[4 * s], v[4 * s + 1], v[4 * s + 2], v[4 * s + 3]);
}

// ---------------------------------------------------------------------------
extern "C" void kernel_launch(void* const* d_in, const int* in_sizes, int n_in,
                              void* d_out, int out_size, void* d_ws, size_t ws_size,
                              hipStream_t stream) {
    const float* h_in = (const float*)d_in[0];
    const float* W    = (const float*)d_in[1];
    const float* b_ih = (const float*)d_in[2];
    const float* b_hh = (const float*)d_in[3];
    float* out = (float*)d_out;

    // Workspace layout (bytes):
    //   Wb     @ 0          : 4096*1024*2 = 8388608
    //   h0     @ 8388608    : 2048*1024*2 = 4194304
    //   h1     @ 12582912   : 2048*1024*2 = 4194304
    //   c      @ 16777216   : 2048*1024*4 = 8388608
    //   bias   @ 25165824   : 4096*4      = 16384
    //   tmp16  @ 25182208   : 16*2048*1024*4 = 134217728
    char* ws = (char*)d_ws;
    ushort_t* Wb   = (ushort_t*)(ws);
    ushort_t* h0   = (ushort_t*)(ws + 8388608);
    ushort_t* h1   = (ushort_t*)(ws + 12582912);
    float*    cst  = (float*)(ws + 16777216);
    float*    bias = (float*)(ws + 25165824);
    float*    tmp16= (float*)(ws + 25182208);

    hipMemsetAsync(cst, 0, (size_t)Nb * Hdim * sizeof(float), stream);

    prep_w<<<(4 * Hdim * Hdim) / 256, 256, 0, stream>>>(W, Wb);
    prep_h<<<(Nb * Hdim) / 256, 256, 0, stream>>>(h_in, h0, b_ih, b_hh, bias);

    for (int t = 0; t < Lsteps; ++t) {
        const ushort_t* hs = (t & 1) ? h1 : h0;
        ushort_t*       hd = (t & 1) ? h0 : h1;
        float* tslot = tmp16 + (size_t)(t & 15) * (Nb * Hdim);
        lstm_step<<<512, 256, 0, stream>>>(hs, hd, Wb, bias, cst, tslot);
        if ((t & 15) == 15) {
            flush16<<<(Nb * Hdim) / 256, 256, 0, stream>>>(tmp16, out, t - 15);
        }
    }
}

// Round 3
// 1884.116 us; speedup vs baseline: 1.2610x; 1.0114x over previous
//
#include <hip/hip_runtime.h>
#include <hip/hip_bf16.h>

// Problem constants
#define Hdim 1024
#define Nb   2048
#define Lsteps 48

typedef unsigned short ushort_t;
typedef short bf16x8 __attribute__((ext_vector_type(8)));   // 8 bf16 (4 VGPRs)
typedef float f32x4 __attribute__((ext_vector_type(4)));    // 4 fp32 accum

typedef __attribute__((address_space(3))) unsigned int lds_u32;
typedef const __attribute__((address_space(1))) unsigned int glb_u32;

__device__ __forceinline__ void gll16(const void* g, void* l) {
    // async global->LDS DMA, 16 B/lane; LDS dest = wave-uniform base + lane*16
    __builtin_amdgcn_global_load_lds((glb_u32*)g, (lds_u32*)l, 16, 0, 0);
}

// RTN-even fp32 -> bf16 bits
__device__ __forceinline__ ushort_t f2bf(float x) {
    unsigned u = __builtin_bit_cast(unsigned, x);
    unsigned r = u + 0x7fffu + ((u >> 16) & 1u);
    return (ushort_t)(r >> 16);
}

__device__ __forceinline__ float fsigmoid(float x) {
    return 1.0f / (1.0f + __expf(-x));
}
__device__ __forceinline__ float ftanh(float x) {
    float xm = fminf(fmaxf(x, -15.0f), 15.0f);
    float e = __expf(2.0f * xm);
    return (e - 1.0f) / (e + 1.0f);
}

__device__ __forceinline__ f32x4 mfma16(bf16x8 a, bf16x8 b, f32x4 c) {
    return __builtin_amdgcn_mfma_f32_16x16x32_bf16(a, b, c, 0, 0, 0);
}

// ---------------------------------------------------------------------------
// Prep kernels
// ---------------------------------------------------------------------------
__global__ __launch_bounds__(256) void prep_w(const float* __restrict__ W,
                                              ushort_t* __restrict__ Wb) {
    int i = blockIdx.x * 256 + threadIdx.x;   // 4M elements
    Wb[i] = f2bf(W[i]);
}

__global__ __launch_bounds__(256) void prep_h(const float* __restrict__ h_in,
                                              ushort_t* __restrict__ h0,
                                              const float* __restrict__ b_ih,
                                              const float* __restrict__ b_hh,
                                              float* __restrict__ bias) {
    int i = blockIdx.x * 256 + threadIdx.x;   // 2M elements
    h0[i] = f2bf(h_in[i]);
    if (i < 4 * Hdim) bias[i] = b_ih[i] + b_hh[i];
}

// ---------------------------------------------------------------------------
// Fused step: tile = 128 n-rows x 32 j-cols x 4 gates (GEMM 128x128), BK=64.
// Staging via global_load_lds(16B) into XOR-swizzled unpadded LDS.
//
// XCD-aware block remap: HW dispatch is round-robin, xcd = blockIdx % 8.
// Give each XCD a 4 MB working set that fits its private L2:
//   xcd bit0   -> which half of the n range   (h-slice: 1024 rows = 2 MB)
//   xcd bits1-2-> which quarter of the jb range (W-slice: 1024 rows = 2 MB)
// Its 64 blocks then re-read that slice from L2 instead of L3.
// ---------------------------------------------------------------------------
__global__ __launch_bounds__(256) void lstm_step(
    const ushort_t* __restrict__ hsrc,   // [Nb][Hdim] bf16 bits
    ushort_t* __restrict__ hdst,         // [Nb][Hdim] bf16 bits
    const ushort_t* __restrict__ Wb,     // [4*Hdim][Hdim] bf16 bits
    const float* __restrict__ bias,      // [4*Hdim]
    float* __restrict__ cst,             // [Nb][Hdim] fp32 cell state
    float* __restrict__ tmp)             // [Nb][Hdim] fp32 h output slot
{
    // 128 rows x 64 elems (128 B) each, unpadded (gll requirement).
    __shared__ __align__(16) ushort_t As[128 * 64];    // 16 KB
    __shared__ __align__(16) ushort_t Bs[128 * 64];    // 16 KB

    const int tid  = threadIdx.x;
    const int lane = tid & 63;
    const int wid  = tid >> 6;
    const int wr   = wid >> 1;            // n half (0..1)
    const int wc   = wid & 1;             // j half (0..1)

    // XCD-aware remap: p%8 = XCD (HW round-robin), 64 slots per XCD.
    const int p    = blockIdx.x;
    const int xcd  = p & 7;
    const int slot = p >> 3;              // 0..63
    const int jb   = (xcd >> 1) * 8 + (slot & 7);   // 0..31
    const int nb   = (xcd & 1) * 8 + (slot >> 3);   // 0..15
    const int n0   = nb * 128;
    const int j0   = jb * 32;

    f32x4 acc[4][4];
#pragma unroll
    for (int g = 0; g < 4; ++g)
#pragma unroll
        for (int ri = 0; ri < 4; ++ri)
            acc[g][ri] = (f32x4){0.f, 0.f, 0.f, 0.f};

    // staging geometry: per gll instr, 8 rows x 128 B; lane -> (row, chunk)
    const int srow8  = lane >> 3;                      // row within group of 8
    const int schunk = (lane & 7) ^ srow8;             // swizzled 16B chunk
    const int choff  = schunk * 8;                     // elem offset in row

    // per-lane global row base pointers (row stride Hdim elems)
    const ushort_t* aGlob = hsrc + (size_t)(n0 + wid * 32 + srow8) * Hdim + choff;
    const ushort_t* bGlob = Wb + (size_t)(wid * Hdim + j0 + srow8) * Hdim + choff;

    // ds_read swizzle: row&7 == lr&7 for both A and B fragment rows
    const int lr   = lane & 15;
    const int rsw  = lr & 7;
    const int cq   = lane >> 4;                        // base chunk 0..3

    for (int it = 0; it < 16; ++it) {
        const int k0 = it * 64;
        __syncthreads();
#pragma unroll
        for (int ii = 0; ii < 4; ++ii) {
            gll16(aGlob + (size_t)ii * 8 * Hdim + k0, &As[(wid * 32 + ii * 8) * 64]);
        }
#pragma unroll
        for (int ii = 0; ii < 4; ++ii) {
            gll16(bGlob + (size_t)ii * 8 * Hdim + k0, &Bs[(wid * 32 + ii * 8) * 64]);
        }
        __syncthreads();

#pragma unroll
        for (int kh = 0; kh < 2; ++kh) {
            const int ch = ((cq + kh * 4) ^ rsw) * 8;  // swizzled elem offset
            bf16x8 af[4], bfr[4];
#pragma unroll
            for (int ri = 0; ri < 4; ++ri) {
                int row = wr * 64 + ri * 16 + lr;
                af[ri] = *(const bf16x8*)&As[row * 64 + ch];
            }
#pragma unroll
            for (int g = 0; g < 4; ++g) {
                int u = g * 32 + wc * 16 + lr;
                bfr[g] = *(const bf16x8*)&Bs[u * 64 + ch];
            }
#pragma unroll
            for (int g = 0; g < 4; ++g)
#pragma unroll
                for (int ri = 0; ri < 4; ++ri)
                    acc[g][ri] = mfma16(af[ri], bfr[g], acc[g][ri]);
        }
    }

    // Epilogue: C/D layout col=lane&15, row=(lane>>4)*4+reg  [m89-verified]
    const int q4 = (lane >> 4) * 4;
    const int j  = j0 + wc * 16 + lr;
    const float bi = bias[j];
    const float bf = bias[Hdim + j];
    const float bg = bias[2 * Hdim + j];
    const float bo = bias[3 * Hdim + j];
#pragma unroll
    for (int ri = 0; ri < 4; ++ri)
#pragma unroll
        for (int q = 0; q < 4; ++q) {
            int n = n0 + wr * 64 + ri * 16 + q4 + q;
            float gi = fsigmoid(acc[0][ri][q] + bi);
            float gf = fsigmoid(acc[1][ri][q] + bf);
            float gg = ftanh(acc[2][ri][q] + bg);
            float go = fsigmoid(acc[3][ri][q] + bo);
            size_t idx = (size_t)n * Hdim + j;
            float cn = gf * cst[idx] + gi * gg;
            cst[idx] = cn;
            float hv = go * ftanh(cn);
            hdst[idx] = f2bf(hv);
            tmp[idx] = hv;
        }
}

// ---------------------------------------------------------------------------
// Flush: tmp[16][Nb][Hdim] -> out[n][j][t0 : t0+16]  (full 64B lines)
// ---------------------------------------------------------------------------
__global__ __launch_bounds__(256) void flush16(const float* __restrict__ tmp,
                                               float* __restrict__ out, int t0) {
    int idx = blockIdx.x * 256 + threadIdx.x;   // 0 .. Nb*Hdim-1
    float v[16];
#pragma unroll
    for (int s = 0; s < 16; ++s)
        v[s] = tmp[(size_t)s * (Nb * Hdim) + idx];
    float4* dst = (float4*)(out + (size_t)idx * Lsteps + t0);
#pragma unroll
    for (int s = 0; s < 4; ++s)
        dst[s] = make_float4(v[4 * s], v[4 * s + 1], v[4 * s + 2], v[4 * s + 3]);
}

// ---------------------------------------------------------------------------
extern "C" void kernel_launch(void* const* d_in, const int* in_sizes, int n_in,
                              void* d_out, int out_size, void* d_ws, size_t ws_size,
                              hipStream_t stream) {
    const float* h_in = (const float*)d_in[0];
    const float* W    = (const float*)d_in[1];
    const float* b_ih = (const float*)d_in[2];
    const float* b_hh = (const float*)d_in[3];
    float* out = (float*)d_out;

    // Workspace layout (bytes):
    //   Wb     @ 0          : 4096*1024*2 = 8388608
    //   h0     @ 8388608    : 2048*1024*2 = 4194304
    //   h1     @ 12582912   : 2048*1024*2 = 4194304
    //   c      @ 16777216   : 2048*1024*4 = 8388608
    //   bias   @ 25165824   : 4096*4      = 16384
    //   tmp16  @ 25182208   : 16*2048*1024*4 = 134217728
    char* ws = (char*)d_ws;
    ushort_t* Wb   = (ushort_t*)(ws);
    ushort_t* h0   = (ushort_t*)(ws + 8388608);
    ushort_t* h1   = (ushort_t*)(ws + 12582912);
    float*    cst  = (float*)(ws + 16777216);
    float*    bias = (float*)(ws + 25165824);
    float*    tmp16= (float*)(ws + 25182208);

    hipMemsetAsync(cst, 0, (size_t)Nb * Hdim * sizeof(float), stream);

    prep_w<<<(4 * Hdim * Hdim) / 256, 256, 0, stream>>>(W, Wb);
    prep_h<<<(Nb * Hdim) / 256, 256, 0, stream>>>(h_in, h0, b_ih, b_hh, bias);

    for (int t = 0; t < Lsteps; ++t) {
        const ushort_t* hs = (t & 1) ? h1 : h0;
        ushort_t*       hd = (t & 1) ? h0 : h1;
        float* tslot = tmp16 + (size_t)(t & 15) * (Nb * Hdim);
        lstm_step<<<512, 256, 0, stream>>>(hs, hd, Wb, bias, cst, tslot);
        if ((t & 15) == 15) {
            flush16<<<(Nb * Hdim) / 256, 256, 0, stream>>>(tmp16, out, t - 15);
        }
    }
}